// Round 3
// baseline (832.616 us; speedup 1.0000x reference)
//
#include <hip/hip_runtime.h>
#include <hip/hip_bf16.h>
#include <stdint.h>

// Problem constants (fixed by setup_inputs)
#define E_ 8
#define C_ 2048
#define H_ 2048
#define I_ 2816
#define N1_ (2 * I_)   // 5632

typedef __attribute__((ext_vector_type(8))) short bf16x8;
typedef __attribute__((ext_vector_type(4))) float f32x4;

__device__ __forceinline__ unsigned short f2bf(float f) {
  union { float f; unsigned int u; } v; v.f = f;
  unsigned int u = v.u;
  unsigned int r = (u + 0x7FFFu + ((u >> 16) & 1u)) >> 16;  // RNE
  return (unsigned short)r;
}

__device__ __forceinline__ unsigned int pkbf(float a, float b) {
  union { __hip_bfloat162 h; unsigned int u; } cv;
  cv.h = __float22bfloat162_rn(make_float2(a, b));
  return cv.u;
}

__device__ __forceinline__ void gload16(const unsigned short* g, char* l) {
  __builtin_amdgcn_global_load_lds(
      (const __attribute__((address_space(1))) unsigned int*)g,
      (__attribute__((address_space(3))) unsigned int*)l, 16, 0, 0);
}

#define BARX()  do { asm volatile("" ::: "memory"); __builtin_amdgcn_s_barrier(); asm volatile("" ::: "memory"); } while (0)
#define LGKM0() asm volatile("s_waitcnt lgkmcnt(0)" ::: "memory")
#define VMC(n)  asm volatile("s_waitcnt vmcnt(" #n ")" ::: "memory")
#define PRIO(p) __builtin_amdgcn_s_setprio(p)
// select float4 component by unroll-constant index
#define FC(v, c) ((c) == 0 ? (v).x : (c) == 1 ? (v).y : (c) == 2 ? (v).z : (v).w)

// ---------------- fp32 -> bf16 straight conversion (vectorized 8/thread) ----
__global__ __launch_bounds__(256) void cvt_bf16(const float* __restrict__ src,
                                                unsigned short* __restrict__ dst,
                                                int n8) {
  int idx = blockIdx.x * 256 + threadIdx.x;
  int stride = gridDim.x * 256;
  for (int i = idx; i < n8; i += stride) {
    const float4* s = (const float4*)(src + (size_t)i * 8);
    float4 a = s[0], b = s[1];
    uint4 o;
    o.x = (unsigned int)f2bf(a.x) | ((unsigned int)f2bf(a.y) << 16);
    o.y = (unsigned int)f2bf(a.z) | ((unsigned int)f2bf(a.w) << 16);
    o.z = (unsigned int)f2bf(b.x) | ((unsigned int)f2bf(b.y) << 16);
    o.w = (unsigned int)f2bf(b.z) | ((unsigned int)f2bf(b.w) << 16);
    *(uint4*)(dst + (size_t)i * 8) = o;
  }
}

// Shared frag-read macros -----------------------------------------------------
// A tiles: linear [256 rows][128B], gload_lds-staged, XOR2 chunk swizzle.
#define RDA(buf, m4) \
  _Pragma("unroll") for (int mi = 0; mi < 4; ++mi) \
  _Pragma("unroll") for (int kk = 0; kk < 2; ++kk) { \
    const int rw = ar + ((m4) + mi) * 16; \
    fa[mi][kk] = *(const bf16x8*)((buf) + rw * 128 + ((((kk << 2) | kb) ^ (rw & 7)) << 4)); }

// B tiles: [256 rows][128B], reg-staged, XOR3 chunk swizzle.
#define BCHUNK(rw, ch) ((((ch) ^ ((rw) & 7) ^ (((rw) >> 3) & 7))) << 4)

// ===================== GEMM1: 256x128 dual-B 8-phase GLU ====================
// A: [E][C][H] bf16 (k-major, gload_lds). W: fp32 [E][H][2I] (reg-staged).
// act: [E][C][I] bf16. 8 waves (2Mx4N): wave output 128 rows x 32 cols x {g,u}.
__global__ __launch_bounds__(512, 2) void gemm1_glu(const unsigned short* __restrict__ A,
                                                    const float* __restrict__ W,
                                                    unsigned short* __restrict__ act) {
  constexpr int MT = C_ / 256;   // 8
  constexpr int NT = I_ / 128;   // 22
  constexpr int NK = H_ / 64;    // 32
  constexpr int NIT = NK / 2;    // 16
  const int nwg = E_ * MT * NT;  // 1408
  int bid = blockIdx.x;
  int swz = (bid & 7) * (nwg >> 3) + (bid >> 3);
  int e = swz / (MT * NT);
  int r2 = swz % (MT * NT);
  int m0 = (r2 % MT) << 8;
  int n0 = (r2 / MT) << 7;

  const unsigned short* Ae = A + (size_t)e * C_ * H_ + (size_t)m0 * H_;
  const float* We = W + (size_t)e * H_ * N1_;
  unsigned short* Ce = act + (size_t)e * C_ * I_;

  __shared__ char lds[131072];
  char* const A0b = lds;
  char* const A1b = lds + 32768;
  char* const B0b = lds + 65536;
  char* const B1b = lds + 98304;

  const int t = threadIdx.x, lane = t & 63, w = t >> 6;
  const int wr = (w >> 2) << 7;   // 0 / 128
  const int wc = (w & 3) << 5;    // 0,32,64,96

  const int la = lane & 15, kb = lane >> 4;
  const int ar = wr + la;
  const int brr = wc + la;

  // A staging (gload_lds linear): thread -> (row t>>3, chunk t&7), src XOR2-preswizzled
  const int sr0 = t >> 3, sc0 = t & 7;
  const int sofA = sr0 * H_ + ((sc0 ^ (sr0 & 7)) << 3);
  const int dof = t << 4;

#define AGL4(ko, lb) do { \
    gload16(Ae + (ko) + sofA,            (lb) + dof); \
    gload16(Ae + (ko) + sofA +  64 * H_, (lb) + dof + 8192); \
    gload16(Ae + (ko) + sofA + 128 * H_, (lb) + dof + 16384); \
    gload16(Ae + (ko) + sofA + 192 * H_, (lb) + dof + 24576); } while (0)

  // B staging (reg): thread owns 4 n-cols x 8 k; cg = t&63 (LDS rows 4cg..4cg+3),
  // kcw = wave idx = k-chunk. gate rows 0..127 (cols n0+..), up rows 128..255 (cols n0+I+..)
  const int cg = t & 63, kcw = t >> 6;
  const int nglob = n0 + (cg & 31) * 4 + (cg >> 5) * I_;
  const float* Wb = We + (size_t)kcw * 8 * N1_ + nglob;
  int wbof[4];
#pragma unroll
  for (int c = 0; c < 4; ++c) {
    const int rw = cg * 4 + c;
    wbof[c] = rw * 128 + BCHUNK(rw, kcw);
  }

  float4 br[8];
#define BLD(ko, j0) \
  _Pragma("unroll") for (int j = 0; j < 4; ++j) \
    br[(j0) + j] = *(const float4*)(Wb + (size_t)((ko) + (j0) + j) * N1_);

#define BWR(lb) do { \
    _Pragma("unroll") for (int c = 0; c < 4; ++c) { \
      uint4 pk; \
      pk.x = pkbf(FC(br[0], c), FC(br[1], c)); \
      pk.y = pkbf(FC(br[2], c), FC(br[3], c)); \
      pk.z = pkbf(FC(br[4], c), FC(br[5], c)); \
      pk.w = pkbf(FC(br[6], c), FC(br[7], c)); \
      *(uint4*)((lb) + wbof[c]) = pk; \
    } } while (0)

#define RDBG(buf, dst, ro) \
  _Pragma("unroll") for (int ni = 0; ni < 2; ++ni) \
  _Pragma("unroll") for (int kk = 0; kk < 2; ++kk) { \
    const int rw = (ro) + brr + ni * 16; \
    dst[ni][kk] = *(const bf16x8*)((buf) + rw * 128 + BCHUNK(rw, (kk << 2) | kb)); }

#define MMG(accA, m4, bfr) \
  _Pragma("unroll") for (int mi = 0; mi < 4; ++mi) \
  _Pragma("unroll") for (int ni = 0; ni < 2; ++ni) \
  _Pragma("unroll") for (int kk = 0; kk < 2; ++kk) \
    accA[(m4) + mi][ni] = __builtin_amdgcn_mfma_f32_16x16x32_bf16(fa[mi][kk], bfr[ni][kk], accA[(m4) + mi][ni], 0, 0, 0);

  f32x4 accg[8][2] = {};
  f32x4 accu[8][2] = {};
  bf16x8 fa[4][2], fg[2][2], fu[2][2];

  // ---- prologue: tiles 0,1 ----
  AGL4(0, A0b);
  AGL4(64, A1b);
  BLD(0, 0); BLD(0, 4);
  VMC(0);
  BWR(B0b);
  BLD(64, 0); BLD(64, 4);
  VMC(0);
  BWR(B1b);
  LGKM0(); BARX();

#pragma unroll 1
  for (int i = 0; i < NIT - 1; ++i) {
    const int kc = i * 128;
    // ph1
    RDA(A0b, 0); RDBG(B0b, fg, 0);
    BLD(kc + 128, 0);
    BARX(); LGKM0();
    PRIO(1); MMG(accg, 0, fg); PRIO(0); BARX();
    // ph2
    RDBG(B0b, fu, 128);
    BLD(kc + 128, 4);
    BARX(); LGKM0();
    PRIO(1); MMG(accu, 0, fu); PRIO(0); BARX();
    // ph3
    RDA(A0b, 4);
    BARX(); LGKM0();
    PRIO(1); MMG(accg, 4, fg); PRIO(0); BARX();
    // ph4: A(T+2) gloads; VMC(4) -> prev A landed + B regs ready; write B(T+2)
    AGL4(kc + 128, A0b);
    VMC(4);
    BWR(B0b);
    BARX(); LGKM0();
    PRIO(1); MMG(accu, 4, fu); PRIO(0); BARX();
    // ph5
    RDA(A1b, 0); RDBG(B1b, fg, 0);
    BLD(kc + 192, 0);
    BARX(); LGKM0();
    PRIO(1); MMG(accg, 0, fg); PRIO(0); BARX();
    // ph6
    RDBG(B1b, fu, 128);
    BLD(kc + 192, 4);
    BARX(); LGKM0();
    PRIO(1); MMG(accu, 0, fu); PRIO(0); BARX();
    // ph7
    RDA(A1b, 4);
    BARX(); LGKM0();
    PRIO(1); MMG(accg, 4, fg); PRIO(0); BARX();
    // ph8
    AGL4(kc + 192, A1b);
    VMC(4);
    BWR(B1b);
    BARX(); LGKM0();
    PRIO(1); MMG(accu, 4, fu); PRIO(0); BARX();
  }

  // ---- peeled last iteration (no prefetch) ----
  VMC(0); BARX();
  RDA(A0b, 0); RDBG(B0b, fg, 0);
  BARX(); LGKM0(); PRIO(1); MMG(accg, 0, fg); PRIO(0); BARX();
  RDBG(B0b, fu, 128);
  BARX(); LGKM0(); PRIO(1); MMG(accu, 0, fu); PRIO(0); BARX();
  RDA(A0b, 4);
  BARX(); LGKM0(); PRIO(1); MMG(accg, 4, fg); PRIO(0); BARX();
  BARX(); PRIO(1); MMG(accu, 4, fu); PRIO(0); BARX();
  RDA(A1b, 0); RDBG(B1b, fg, 0);
  BARX(); LGKM0(); PRIO(1); MMG(accg, 0, fg); PRIO(0); BARX();
  RDBG(B1b, fu, 128);
  BARX(); LGKM0(); PRIO(1); MMG(accu, 0, fu); PRIO(0); BARX();
  RDA(A1b, 4);
  BARX(); LGKM0(); PRIO(1); MMG(accg, 4, fg); PRIO(0); BARX();
  PRIO(1); MMG(accu, 4, fu); PRIO(0);

  // Epilogue: act = silu(g) * u. C/D layout: col=lane&15, row=(lane>>4)*4+reg
  const int rb = m0 + wr + (kb << 2);
  const int cb = n0 + wc + la;
#pragma unroll
  for (int mi = 0; mi < 8; ++mi)
#pragma unroll
    for (int ni = 0; ni < 2; ++ni)
#pragma unroll
      for (int r = 0; r < 4; ++r) {
        float g = accg[mi][ni][r], u = accu[mi][ni][r];
        float s = g / (1.0f + __expf(-g));
        Ce[(size_t)(rb + mi * 16 + r) * I_ + (cb + ni * 16)] = f2bf(s * u);
      }
#undef AGL4
#undef BLD
#undef BWR
}

// ===================== GEMM2: 256x256 8-phase, fp32 out =====================
// A: [E][C][I] bf16 (gload_lds). W: fp32 [E][I][H] (reg-staged). Out: fp32.
__global__ __launch_bounds__(512, 2) void gemm2_down(const unsigned short* __restrict__ A,
                                                     const float* __restrict__ W,
                                                     float* __restrict__ Out) {
  constexpr int MT = C_ / 256;   // 8
  constexpr int NT = H_ / 256;   // 8
  constexpr int NK = I_ / 64;    // 44
  constexpr int NIT = NK / 2;    // 22
  const int nwg = E_ * MT * NT;  // 512
  int bid = blockIdx.x;
  int swz = (bid & 7) * (nwg >> 3) + (bid >> 3);
  int e = swz / (MT * NT);
  int r2 = swz % (MT * NT);
  int m0 = (r2 % MT) << 8;
  int n0 = (r2 / MT) << 8;

  const unsigned short* Ae = A + (size_t)e * C_ * I_ + (size_t)m0 * I_;
  const float* We = W + (size_t)e * I_ * H_;
  float* Oe = Out + (size_t)e * C_ * H_;

  __shared__ char lds[131072];
  char* const A0b = lds;
  char* const A1b = lds + 32768;
  char* const B0b = lds + 65536;
  char* const B1b = lds + 98304;

  const int t = threadIdx.x, lane = t & 63, w = t >> 6;
  const int wr = (w >> 2) << 7;   // 0 / 128
  const int wc = (w & 3) << 6;    // 0,64,128,192

  const int la = lane & 15, kb = lane >> 4;
  const int ar = wr + la;
  const int brr = wc + la;

  const int sr0 = t >> 3, sc0 = t & 7;
  const int sofA = sr0 * I_ + ((sc0 ^ (sr0 & 7)) << 3);
  const int dof = t << 4;

#define AGL4(ko, lb) do { \
    gload16(Ae + (ko) + sofA,            (lb) + dof); \
    gload16(Ae + (ko) + sofA +  64 * I_, (lb) + dof + 8192); \
    gload16(Ae + (ko) + sofA + 128 * I_, (lb) + dof + 16384); \
    gload16(Ae + (ko) + sofA + 192 * I_, (lb) + dof + 24576); } while (0)

  const int cg = t & 63, kcw = t >> 6;
  const int nglob = n0 + cg * 4;
  const float* Wb = We + (size_t)kcw * 8 * H_ + nglob;
  int wbof[4];
#pragma unroll
  for (int c = 0; c < 4; ++c) {
    const int rw = cg * 4 + c;
    wbof[c] = rw * 128 + BCHUNK(rw, kcw);
  }

  float4 br[8];
#define BLD(ko, j0) \
  _Pragma("unroll") for (int j = 0; j < 4; ++j) \
    br[(j0) + j] = *(const float4*)(Wb + (size_t)((ko) + (j0) + j) * H_);

#define BWR(lb) do { \
    _Pragma("unroll") for (int c = 0; c < 4; ++c) { \
      uint4 pk; \
      pk.x = pkbf(FC(br[0], c), FC(br[1], c)); \
      pk.y = pkbf(FC(br[2], c), FC(br[3], c)); \
      pk.z = pkbf(FC(br[4], c), FC(br[5], c)); \
      pk.w = pkbf(FC(br[6], c), FC(br[7], c)); \
      *(uint4*)((lb) + wbof[c]) = pk; \
    } } while (0)

#define RDB2(buf, n2) \
  _Pragma("unroll") for (int ni = 0; ni < 2; ++ni) \
  _Pragma("unroll") for (int kk = 0; kk < 2; ++kk) { \
    const int rw = brr + ((n2) + ni) * 16; \
    fb[(n2) + ni][kk] = *(const bf16x8*)((buf) + rw * 128 + BCHUNK(rw, (kk << 2) | kb)); }

#define MM4(m4, n2) \
  _Pragma("unroll") for (int mi = 0; mi < 4; ++mi) \
  _Pragma("unroll") for (int ni = 0; ni < 2; ++ni) \
  _Pragma("unroll") for (int kk = 0; kk < 2; ++kk) \
    acc[(m4) + mi][(n2) + ni] = __builtin_amdgcn_mfma_f32_16x16x32_bf16(fa[mi][kk], fb[(n2) + ni][kk], acc[(m4) + mi][(n2) + ni], 0, 0, 0);

  f32x4 acc[8][4] = {};
  bf16x8 fa[4][2], fb[4][2];

  // ---- prologue ----
  AGL4(0, A0b);
  AGL4(64, A1b);
  BLD(0, 0); BLD(0, 4);
  VMC(0);
  BWR(B0b);
  BLD(64, 0); BLD(64, 4);
  VMC(0);
  BWR(B1b);
  LGKM0(); BARX();

#pragma unroll 1
  for (int i = 0; i < NIT - 1; ++i) {
    const int kc = i * 128;
    // ph1
    RDA(A0b, 0); RDB2(B0b, 0);
    BLD(kc + 128, 0);
    BARX(); LGKM0();
    PRIO(1); MM4(0, 0); PRIO(0); BARX();
    // ph2
    RDB2(B0b, 2);
    BLD(kc + 128, 4);
    BARX(); LGKM0();
    PRIO(1); MM4(0, 2); PRIO(0); BARX();
    // ph3
    RDA(A0b, 4);
    BARX(); LGKM0();
    PRIO(1); MM4(4, 0); PRIO(0); BARX();
    // ph4
    AGL4(kc + 128, A0b);
    VMC(4);
    BWR(B0b);
    BARX(); LGKM0();
    PRIO(1); MM4(4, 2); PRIO(0); BARX();
    // ph5
    RDA(A1b, 0); RDB2(B1b, 0);
    BLD(kc + 192, 0);
    BARX(); LGKM0();
    PRIO(1); MM4(0, 0); PRIO(0); BARX();
    // ph6
    RDB2(B1b, 2);
    BLD(kc + 192, 4);
    BARX(); LGKM0();
    PRIO(1); MM4(0, 2); PRIO(0); BARX();
    // ph7
    RDA(A1b, 4);
    BARX(); LGKM0();
    PRIO(1); MM4(4, 0); PRIO(0); BARX();
    // ph8
    AGL4(kc + 192, A1b);
    VMC(4);
    BWR(B1b);
    BARX(); LGKM0();
    PRIO(1); MM4(4, 2); PRIO(0); BARX();
  }

  // ---- peeled last iteration ----
  VMC(0); BARX();
  RDA(A0b, 0); RDB2(B0b, 0);
  BARX(); LGKM0(); PRIO(1); MM4(0, 0); PRIO(0); BARX();
  RDB2(B0b, 2);
  BARX(); LGKM0(); PRIO(1); MM4(0, 2); PRIO(0); BARX();
  RDA(A0b, 4);
  BARX(); LGKM0(); PRIO(1); MM4(4, 0); PRIO(0); BARX();
  BARX(); PRIO(1); MM4(4, 2); PRIO(0); BARX();
  RDA(A1b, 0); RDB2(B1b, 0);
  BARX(); LGKM0(); PRIO(1); MM4(0, 0); PRIO(0); BARX();
  RDB2(B1b, 2);
  BARX(); LGKM0(); PRIO(1); MM4(0, 2); PRIO(0); BARX();
  RDA(A1b, 4);
  BARX(); LGKM0(); PRIO(1); MM4(4, 0); PRIO(0); BARX();
  PRIO(1); MM4(4, 2); PRIO(0);

  const int rb = m0 + wr + (kb << 2);
  const int cb = n0 + wc + la;
#pragma unroll
  for (int mi = 0; mi < 8; ++mi)
#pragma unroll
    for (int ni = 0; ni < 4; ++ni)
#pragma unroll
      for (int r = 0; r < 4; ++r)
        Oe[(size_t)(rb + mi * 16 + r) * H_ + (cb + ni * 16)] = acc[mi][ni][r];
}

extern "C" void kernel_launch(void* const* d_in, const int* in_sizes, int n_in,
                              void* d_out, int out_size, void* d_ws, size_t ws_size,
                              hipStream_t stream) {
  const float* hidden = (const float*)d_in[0];
  const float* gateup = (const float*)d_in[1];
  const float* down = (const float*)d_in[2];
  float* out = (float*)d_out;

  unsigned short* ws = (unsigned short*)d_ws;
  unsigned short* hiddenB = ws;                                   // E*C*H bf16
  unsigned short* actB = hiddenB + (size_t)E_ * C_ * H_;          // E*C*I bf16

  cvt_bf16<<<2048, 256, 0, stream>>>(hidden, hiddenB, (E_ * C_ * H_) / 8);
  gemm1_glu<<<E_ * (C_ / 256) * (I_ / 128), 512, 0, stream>>>(hiddenB, gateup, actB);
  gemm2_down<<<E_ * (C_ / 256) * (H_ / 256), 512, 0, stream>>>(actB, down, out);
}

// Round 4
// 712.552 us; speedup vs baseline: 1.1685x; 1.1685x over previous
//
#include <hip/hip_runtime.h>
#include <hip/hip_bf16.h>
#include <stdint.h>

// Problem constants (fixed by setup_inputs)
#define E_ 8
#define C_ 2048
#define H_ 2048
#define I_ 2816
#define N1_ (2 * I_)   // 5632

typedef __attribute__((ext_vector_type(8))) short bf16x8;
typedef __attribute__((ext_vector_type(4))) float f32x4;

__device__ __forceinline__ unsigned short f2bf(float f) {
  union { float f; unsigned int u; } v; v.f = f;
  unsigned int u = v.u;
  unsigned int r = (u + 0x7FFFu + ((u >> 16) & 1u)) >> 16;  // RNE
  return (unsigned short)r;
}

__device__ __forceinline__ void gload16(const unsigned short* g, char* l) {
  __builtin_amdgcn_global_load_lds(
      (const __attribute__((address_space(1))) unsigned int*)g,
      (__attribute__((address_space(3))) unsigned int*)l, 16, 0, 0);
}

#define BARX()  do { asm volatile("" ::: "memory"); __builtin_amdgcn_s_barrier(); asm volatile("" ::: "memory"); } while (0)
#define LGKM0() asm volatile("s_waitcnt lgkmcnt(0)" ::: "memory")
#define VMC(n)  asm volatile("s_waitcnt vmcnt(" #n ")" ::: "memory")
#define PRIO(p) __builtin_amdgcn_s_setprio(p)

// ---------------- fp32 -> bf16 straight conversion (vectorized 8/thread) ----
__global__ __launch_bounds__(256) void cvt_bf16(const float* __restrict__ src,
                                                unsigned short* __restrict__ dst,
                                                int n8) {
  int idx = blockIdx.x * 256 + threadIdx.x;
  int stride = gridDim.x * 256;
  for (int i = idx; i < n8; i += stride) {
    const float4* s = (const float4*)(src + (size_t)i * 8);
    float4 a = s[0], b = s[1];
    uint4 o;
    o.x = (unsigned int)f2bf(a.x) | ((unsigned int)f2bf(a.y) << 16);
    o.y = (unsigned int)f2bf(a.z) | ((unsigned int)f2bf(a.w) << 16);
    o.z = (unsigned int)f2bf(b.x) | ((unsigned int)f2bf(b.y) << 16);
    o.w = (unsigned int)f2bf(b.z) | ((unsigned int)f2bf(b.w) << 16);
    *(uint4*)(dst + (size_t)i * 8) = o;
  }
}

// ------- fp32 [R][C] -> bf16 [C][R] per-expert transpose, 64c x 256r tiles --
// Output rows get 512B contiguous runs; LDS stride 264 => 16B-aligned,
// conflict-free read-back.
__global__ __launch_bounds__(256) void transpose_cvt(const float* __restrict__ src,
                                                     unsigned short* __restrict__ dst,
                                                     int R, int C) {
  int tilesC = C >> 6, tilesR = R >> 8;
  int tiles = tilesR * tilesC;
  int bid = blockIdx.x;
  int e = bid / tiles;
  int r2 = bid % tiles;
  int tr = r2 / tilesC, tc = r2 % tilesC;
  const float* s = src + (size_t)e * R * C + (size_t)(tr << 8) * C + (tc << 6);
  unsigned short* d = dst + (size_t)e * R * C + (size_t)(tc << 6) * R + (tr << 8);

  __shared__ unsigned short lds[64 * 264];
  int t = threadIdx.x;
  int tx = t & 15, ty = t >> 4;
#pragma unroll
  for (int p = 0; p < 16; ++p) {
    int row = p * 16 + ty;
    float4 v = *(const float4*)(s + (size_t)row * C + tx * 4);
    int cb = tx * 4;
    lds[(cb + 0) * 264 + row] = f2bf(v.x);
    lds[(cb + 1) * 264 + row] = f2bf(v.y);
    lds[(cb + 2) * 264 + row] = f2bf(v.z);
    lds[(cb + 3) * 264 + row] = f2bf(v.w);
  }
  __syncthreads();
#pragma unroll
  for (int it = 0; it < 8; ++it) {
    int q = it * 256 + t;
    int c = q >> 5, ro = (q & 31) * 8;
    uint4 vv = *(const uint4*)(&lds[c * 264 + ro]);
    *(uint4*)(d + (size_t)c * R + ro) = vv;
  }
}

// Shared frag-read macro: A/B tiles linear [rows][128B], XOR2 chunk swizzle.
#define RDA(buf, m4) \
  _Pragma("unroll") for (int mi = 0; mi < 4; ++mi) \
  _Pragma("unroll") for (int kk = 0; kk < 2; ++kk) \
    fa[(m4) + mi][kk] = *(const bf16x8*)((buf) + (ar + ((m4) + mi) * 16) * 128 + ((((kk << 2) | kb) ^ s7a) << 4));

// ===================== GEMM1: 256x128 dual-B 8-phase GLU ====================
// A: [E][C][H] bf16 (k-major). BT: [E][2I][H] bf16 (n-major). act: [E][C][I] bf16.
// 8 waves (2Mx4N): wave output 128 rows x 32 cols x {gate, up}.
__global__ __launch_bounds__(512, 2) void gemm1_glu(const unsigned short* __restrict__ A,
                                                    const unsigned short* __restrict__ BT,
                                                    unsigned short* __restrict__ act) {
  constexpr int MT = C_ / 256;   // 8
  constexpr int NT = I_ / 128;   // 22
  constexpr int NK = H_ / 64;    // 32
  constexpr int NIT = NK / 2;    // 16
  const int nwg = E_ * MT * NT;  // 1408
  int bid = blockIdx.x;
  int swz = (bid & 7) * (nwg >> 3) + (bid >> 3);
  int e = swz / (MT * NT);
  int r2 = swz % (MT * NT);
  int m0 = (r2 % MT) << 8;
  int n0 = (r2 / MT) << 7;

  const unsigned short* Ae = A + (size_t)e * C_ * H_ + (size_t)m0 * H_;
  const unsigned short* Ge = BT + (size_t)e * N1_ * H_ + (size_t)n0 * H_;
  const unsigned short* Ue = Ge + (size_t)I_ * H_;
  unsigned short* Ce = act + (size_t)e * C_ * I_;

  __shared__ char lds[131072];
  char* const A0b = lds;
  char* const A1b = lds + 32768;
  char* const B0b = lds + 65536;
  char* const B1b = lds + 98304;

  const int t = threadIdx.x, lane = t & 63, w = t >> 6;
  const int wr = (w >> 2) << 7;   // 0 / 128
  const int wc = (w & 3) << 5;    // 0,32,64,96

  const int la = lane & 15, kb = lane >> 4;
  const int ar = wr + la, s7a = ar & 7;
  const int br = wc + la, s7b = br & 7;

  const int sr0 = t >> 3, sc0 = t & 7;
  const int sof0 = sr0 * H_ + ((sc0 ^ (sr0 & 7)) << 3);
  const int sof1 = sof0 + 64 * H_;
  const int dof0 = t << 4, dof1 = (t << 4) + 8192;

#define STG1(gb, ko, lb) do { \
    gload16((gb) + (ko) + sof0, (lb) + dof0); \
    gload16((gb) + (ko) + sof1, (lb) + dof1); } while (0)

#define RDBG(buf, dst, ro) \
  _Pragma("unroll") for (int ni = 0; ni < 2; ++ni) \
  _Pragma("unroll") for (int kk = 0; kk < 2; ++kk) \
    dst[ni][kk] = *(const bf16x8*)((buf) + ((ro) + br + ni * 16) * 128 + ((((kk << 2) | kb) ^ s7b) << 4));

#define MMG(accA, m4, bfr) \
  _Pragma("unroll") for (int mi = 0; mi < 4; ++mi) \
  _Pragma("unroll") for (int ni = 0; ni < 2; ++ni) \
  _Pragma("unroll") for (int kk = 0; kk < 2; ++kk) \
    accA[(m4) + mi][ni] = __builtin_amdgcn_mfma_f32_16x16x32_bf16(fa[(m4) + mi][kk], bfr[ni][kk], accA[(m4) + mi][ni], 0, 0, 0);

  f32x4 accg[8][2] = {};
  f32x4 accu[8][2] = {};
  bf16x8 fa[8][2], fg[2][2], fu[2][2];

  // prologue: tile0 {Ah0,Ah1,Bg,Bu}, tile1 {Ah0,Ah1}
  STG1(Ae, 0, A0b); STG1(Ae + 128 * H_, 0, A0b + 16384);
  STG1(Ge, 0, B0b); STG1(Ue, 0, B0b + 16384);
  STG1(Ae, 64, A1b); STG1(Ae + 128 * H_, 64, A1b + 16384);
  VMC(4); BARX();

#pragma unroll 1
  for (int i = 0; i < NIT; ++i) {
    const int kc = i * 128;
    const bool nx = (i + 1 < NIT);
    // ph1: read a(mh0)+bg from buf0; stage (T+1).Bg -> B1
    RDA(A0b, 0); RDBG(B0b, fg, 0);
    STG1(Ge, kc + 64, B1b);
    BARX(); LGKM0();
    PRIO(1); MMG(accg, 0, fg); PRIO(0); BARX();
    // ph2: read bu; stage (T+1).Bu -> B1
    RDBG(B0b, fu, 128);
    STG1(Ue, kc + 64, B1b + 16384);
    BARX(); LGKM0();
    PRIO(1); MMG(accu, 0, fu); PRIO(0); BARX();
    // ph3: read a(mh1)
    RDA(A0b, 4);
    BARX(); LGKM0();
    PRIO(1); MMG(accg, 4, fg); PRIO(0); BARX();
    // ph4: stage (T+2).A (both halves) -> A0; vmcnt keeps 4 in flight
    if (nx) { STG1(Ae, kc + 128, A0b); STG1(Ae + 128 * H_, kc + 128, A0b + 16384); VMC(4); }
    else VMC(0);
    BARX();
    PRIO(1); MMG(accu, 4, fu); PRIO(0); BARX();
    // ph5: read buf1 a(mh0)+bg; stage (T+2).Bg -> B0
    RDA(A1b, 0); RDBG(B1b, fg, 0);
    if (nx) STG1(Ge, kc + 128, B0b);
    BARX(); LGKM0();
    PRIO(1); MMG(accg, 0, fg); PRIO(0); BARX();
    // ph6: read buf1 bu; stage (T+2).Bu -> B0
    RDBG(B1b, fu, 128);
    if (nx) STG1(Ue, kc + 128, B0b + 16384);
    BARX(); LGKM0();
    PRIO(1); MMG(accu, 0, fu); PRIO(0); BARX();
    // ph7: read buf1 a(mh1)
    RDA(A1b, 4);
    BARX(); LGKM0();
    PRIO(1); MMG(accg, 4, fg); PRIO(0); BARX();
    // ph8: stage (T+3).A (both halves) -> A1
    if (nx) { STG1(Ae, kc + 192, A1b); STG1(Ae + 128 * H_, kc + 192, A1b + 16384); VMC(4); }
    BARX();
    PRIO(1); MMG(accu, 4, fu); PRIO(0); BARX();
  }

  // Epilogue: act = silu(g) * u. C/D layout: col=lane&15, row=(lane>>4)*4+reg
  const int rb = m0 + wr + (kb << 2);
  const int cb = n0 + wc + la;
#pragma unroll
  for (int mi = 0; mi < 8; ++mi)
#pragma unroll
    for (int ni = 0; ni < 2; ++ni)
#pragma unroll
      for (int r = 0; r < 4; ++r) {
        float g = accg[mi][ni][r], u = accu[mi][ni][r];
        float s = g / (1.0f + __expf(-g));
        Ce[(size_t)(rb + mi * 16 + r) * I_ + (cb + ni * 16)] = f2bf(s * u);
      }
#undef STG1
}

// ===================== GEMM2: 256x256 8-phase, fp32 out =====================
// A: [E][C][I] bf16. BT: [E][H][I] bf16 (n-major). Out: [E][C][H] fp32.
__global__ __launch_bounds__(512, 2) void gemm2_down(const unsigned short* __restrict__ A,
                                                     const unsigned short* __restrict__ BT,
                                                     float* __restrict__ Out) {
  constexpr int MT = C_ / 256;   // 8
  constexpr int NT = H_ / 256;   // 8
  constexpr int NK = I_ / 64;    // 44
  constexpr int NIT = NK / 2;    // 22
  const int nwg = E_ * MT * NT;  // 512
  int bid = blockIdx.x;
  int swz = (bid & 7) * (nwg >> 3) + (bid >> 3);
  int e = swz / (MT * NT);
  int r2 = swz % (MT * NT);
  int m0 = (r2 % MT) << 8;
  int n0 = (r2 / MT) << 8;

  const unsigned short* Ae = A + (size_t)e * C_ * I_ + (size_t)m0 * I_;
  const unsigned short* Be = BT + (size_t)e * H_ * I_ + (size_t)n0 * I_;
  float* Oe = Out + (size_t)e * C_ * H_;

  __shared__ char lds[131072];
  char* const A0b = lds;
  char* const A1b = lds + 32768;
  char* const B0b = lds + 65536;
  char* const B1b = lds + 98304;

  const int t = threadIdx.x, lane = t & 63, w = t >> 6;
  const int wr = (w >> 2) << 7;   // 0 / 128
  const int wc = (w & 3) << 6;    // 0,64,128,192

  const int la = lane & 15, kb = lane >> 4;
  const int ar = wr + la, s7a = ar & 7;
  const int br = wc + la, s7b = br & 7;

  const int sr0 = t >> 3, sc0 = t & 7;
  const int sof0 = sr0 * I_ + ((sc0 ^ (sr0 & 7)) << 3);
  const int sof1 = sof0 + 64 * I_;
  const int dof0 = t << 4, dof1 = (t << 4) + 8192;

#define STG2(gb, ko, lb) do { \
    gload16((gb) + (ko) + sof0, (lb) + dof0); \
    gload16((gb) + (ko) + sof1, (lb) + dof1); } while (0)

#define RDB2(buf, n2) \
  _Pragma("unroll") for (int ni = 0; ni < 2; ++ni) \
  _Pragma("unroll") for (int kk = 0; kk < 2; ++kk) \
    fb[(n2) + ni][kk] = *(const bf16x8*)((buf) + (br + ((n2) + ni) * 16) * 128 + ((((kk << 2) | kb) ^ s7b) << 4));

#define MM4(m4, n2) \
  _Pragma("unroll") for (int mi = 0; mi < 4; ++mi) \
  _Pragma("unroll") for (int ni = 0; ni < 2; ++ni) \
  _Pragma("unroll") for (int kk = 0; kk < 2; ++kk) \
    acc[(m4) + mi][(n2) + ni] = __builtin_amdgcn_mfma_f32_16x16x32_bf16(fa[(m4) + mi][kk], fb[(n2) + ni][kk], acc[(m4) + mi][(n2) + ni], 0, 0, 0);

  f32x4 acc[8][4] = {};
  bf16x8 fa[8][2], fb[4][2];

  // prologue
  STG2(Ae, 0, A0b); STG2(Ae + 128 * I_, 0, A0b + 16384);
  STG2(Be, 0, B0b); STG2(Be + 128 * I_, 0, B0b + 16384);
  STG2(Ae, 64, A1b); STG2(Ae + 128 * I_, 64, A1b + 16384);
  VMC(4); BARX();

#pragma unroll 1
  for (int i = 0; i < NIT; ++i) {
    const int kc = i * 128;
    const bool nx = (i + 1 < NIT);
    // ph1
    RDA(A0b, 0); RDB2(B0b, 0);
    STG2(Be, kc + 64, B1b);
    BARX(); LGKM0();
    PRIO(1); MM4(0, 0); PRIO(0); BARX();
    // ph2
    RDB2(B0b, 2);
    STG2(Be + 128 * I_, kc + 64, B1b + 16384);
    BARX(); LGKM0();
    PRIO(1); MM4(0, 2); PRIO(0); BARX();
    // ph3
    RDA(A0b, 4);
    BARX(); LGKM0();
    PRIO(1); MM4(4, 0); PRIO(0); BARX();
    // ph4
    if (nx) { STG2(Ae, kc + 128, A0b); STG2(Ae + 128 * I_, kc + 128, A0b + 16384); VMC(4); }
    else VMC(0);
    BARX();
    PRIO(1); MM4(4, 2); PRIO(0); BARX();
    // ph5
    RDA(A1b, 0); RDB2(B1b, 0);
    if (nx) STG2(Be, kc + 128, B0b);
    BARX(); LGKM0();
    PRIO(1); MM4(0, 0); PRIO(0); BARX();
    // ph6
    RDB2(B1b, 2);
    if (nx) STG2(Be + 128 * I_, kc + 128, B0b + 16384);
    BARX(); LGKM0();
    PRIO(1); MM4(0, 2); PRIO(0); BARX();
    // ph7
    RDA(A1b, 4);
    BARX(); LGKM0();
    PRIO(1); MM4(4, 0); PRIO(0); BARX();
    // ph8
    if (nx) { STG2(Ae, kc + 192, A1b); STG2(Ae + 128 * I_, kc + 192, A1b + 16384); VMC(4); }
    BARX();
    PRIO(1); MM4(4, 2); PRIO(0); BARX();
  }

  const int rb = m0 + wr + (kb << 2);
  const int cb = n0 + wc + la;
#pragma unroll
  for (int mi = 0; mi < 8; ++mi)
#pragma unroll
    for (int ni = 0; ni < 4; ++ni)
#pragma unroll
      for (int r = 0; r < 4; ++r)
        Oe[(size_t)(rb + mi * 16 + r) * H_ + (cb + ni * 16)] = acc[mi][ni][r];
#undef STG2
}

extern "C" void kernel_launch(void* const* d_in, const int* in_sizes, int n_in,
                              void* d_out, int out_size, void* d_ws, size_t ws_size,
                              hipStream_t stream) {
  const float* hidden = (const float*)d_in[0];
  const float* gateup = (const float*)d_in[1];
  const float* down = (const float*)d_in[2];
  float* out = (float*)d_out;

  unsigned short* ws = (unsigned short*)d_ws;
  unsigned short* hiddenB = ws;                                   // E*C*H bf16
  unsigned short* gateupT = hiddenB + (size_t)E_ * C_ * H_;       // E*2I*H bf16 (transposed)
  unsigned short* downT = gateupT + (size_t)E_ * N1_ * H_;        // E*H*I bf16 (transposed)
  unsigned short* actB = downT + (size_t)E_ * I_ * H_;            // E*C*I bf16

  cvt_bf16<<<2048, 256, 0, stream>>>(hidden, hiddenB, (E_ * C_ * H_) / 8);
  transpose_cvt<<<E_ * (H_ / 256) * (N1_ / 64), 256, 0, stream>>>(gateup, gateupT, H_, N1_);
  transpose_cvt<<<E_ * (I_ / 256) * (H_ / 64), 256, 0, stream>>>(down, downT, I_, H_);
  gemm1_glu<<<E_ * (C_ / 256) * (I_ / 128), 512, 0, stream>>>(hiddenB, gateupT, actB);
  gemm2_down<<<E_ * (C_ / 256) * (H_ / 256), 512, 0, stream>>>(actB, downT, out);
}